// Round 12
// baseline (85.762 us; speedup 1.0000x reference)
//
#include <hip/hip_runtime.h>
#include <hip/hip_bf16.h>
#include <math.h>

typedef __attribute__((ext_vector_type(8))) short bf16x8;
typedef __attribute__((ext_vector_type(8))) unsigned short u16x8;
typedef __attribute__((ext_vector_type(4))) float f32x4;
typedef __attribute__((ext_vector_type(16))) float f32x16;

__device__ __forceinline__ unsigned short f2bf(float f) {
  unsigned u = __float_as_uint(f);
  return (unsigned short)((u + 0x7FFFu + ((u >> 16) & 1u)) >> 16);
}
__device__ __forceinline__ float bf2f(unsigned short h) {
  return __uint_as_float(((unsigned)h) << 16);
}
// fp32x8 -> bf16 hi/lo split via packed cvt (compiler emits v_cvt_pk_bf16_f32)
__device__ __forceinline__ void cvt8pk_a(const float* f, u16x8& h, u16x8& l) {
  unsigned* hp = (unsigned*)&h;
  unsigned* lp = (unsigned*)&l;
#pragma unroll
  for (int i = 0; i < 4; ++i) {
    __hip_bfloat162 hb = __float22bfloat162_rn(make_float2(f[2*i], f[2*i+1]));
    unsigned hv = *(unsigned*)&hb;
    hp[i] = hv;
    float r0 = f[2*i]     - __uint_as_float(hv << 16);
    float r1 = f[2*i + 1] - __uint_as_float(hv & 0xFFFF0000u);
    __hip_bfloat162 lb = __float22bfloat162_rn(make_float2(r0, r1));
    lp[i] = *(unsigned*)&lb;
  }
}
__device__ __forceinline__ void cvt8pk(const float4& a, const float4& b,
                                       u16x8& h, u16x8& l) {
  float f[8] = {a.x, a.y, a.z, a.w, b.x, b.y, b.z, b.w};
  cvt8pk_a(f, h, l);
}
__device__ __forceinline__ void cvt8b(const float4& a, const float4& b,
                                      bf16x8& h, bf16x8& l) {
  u16x8 hh, ll;
  cvt8pk(a, b, hh, ll);
  h = *(bf16x8*)&hh;
  l = *(bf16x8*)&ll;
}

#define MFMA32(a, b, c) __builtin_amdgcn_mfma_f32_32x32x16_bf16(a, b, c, 0, 0, 0)

// ---------------------------------------------------------------------------
// K0 (merged): blocks 0-15: split/transpose Wp -> th1/tl1 [kt16][ks8][col128][e8]
//              blocks 16-31: split Wflat -> th2/tl2 [kt2][ks8][col512][e8]
//              blocks 32-95: Gram M[a][c] = Wf[a]·Wf[c], written DIRECTLY in
//                            split-bf16 fragment layout [ks16][col128][e8]
// ---------------------------------------------------------------------------
__global__ __launch_bounds__(256) void caps_prep_all(
    const float* __restrict__ Wp, const float* __restrict__ W,
    unsigned short* __restrict__ th1, unsigned short* __restrict__ tl1,
    unsigned short* __restrict__ th2, unsigned short* __restrict__ tl2,
    unsigned short* __restrict__ th3, unsigned short* __restrict__ tl3)
{
  __shared__ float tile[64][128];
  const int t = threadIdx.x, b = blockIdx.x;
  if (b < 16) {
    const float* src = Wp + (size_t)b * 64 * 128;
#pragma unroll
    for (int i = 0; i < 8; ++i) {
      int j = t + i * 256;
      int kk = j >> 5, q = j & 31;
      *(float4*)&tile[kk][q * 4] = *(const float4*)(src + kk * 128 + q * 4);
    }
    __syncthreads();
    const int col = t >> 1, kg0 = (t & 1) * 4;
    unsigned short hi[32], lo[32];
#pragma unroll
    for (int kk = 0; kk < 32; ++kk) {
      float v = tile[kg0 * 8 + kk][col];
      unsigned short h = f2bf(v);
      hi[kk] = h;
      lo[kk] = f2bf(v - bf2f(h));
    }
#pragma unroll
    for (int i = 0; i < 4; ++i) {
      size_t off = (size_t)b * 8192 + (size_t)(kg0 + i) * 1024 + (size_t)col * 8;
      u16x8 vh, vl;
#pragma unroll
      for (int e = 0; e < 8; ++e) { vh[e] = hi[i * 8 + e]; vl[e] = lo[i * 8 + e]; }
      *(u16x8*)(th1 + off) = vh;
      *(u16x8*)(tl1 + off) = vl;
    }
  } else if (b < 32) {
    int tt = (b - 16) * 256 + t;
#pragma unroll
    for (int h = 0; h < 2; ++h) {
      int c = tt + h * 4096;
      int kt = c >> 12, rem = c & 4095;
      int kg = rem >> 9, col = rem & 511;
      int kbase = kt * 64 + kg * 8;
      u16x8 vh, vl;
#pragma unroll
      for (int e = 0; e < 8; ++e) {
        float v = W[(size_t)(kbase + e) * 512 + col];
        unsigned short hh = f2bf(v);
        vh[e] = hh;
        vl[e] = f2bf(v - bf2f(hh));
      }
      size_t off = ((size_t)(kt * 8 + kg) * 512 + col) * 8;
      *(u16x8*)(th2 + off) = vh;
      *(u16x8*)(tl2 + off) = vl;
    }
  } else {
    int bb = b - 32;
    int a = (bb >> 3) * 16 + (t >> 4);
    int c = (bb & 7) * 16 + (t & 15);
    const float* wa = W + (size_t)a * 512;
    const float* wb = W + (size_t)c * 512;
    float acc = 0.f;
#pragma unroll 4
    for (int o = 0; o < 512; o += 4) {
      float4 xx = *(const float4*)(wa + o);
      float4 yy = *(const float4*)(wb + o);
      acc += xx.x * yy.x + xx.y * yy.y + xx.z * yy.z + xx.w * yy.w;
    }
    unsigned short h = f2bf(acc);
    unsigned short l = f2bf(acc - bf2f(h));
    size_t off = ((size_t)(a >> 3) * 128 + c) * 8 + (a & 7);
    th3[off] = h;
    tl3[off] = l;
  }
}

// ---------------------------------------------------------------------------
// K1: p = squash(x @ Wp + bp), split-bf16 via 32x32x16 MFMA.
// BM=64, BN=128, BK=64, 512 thr (8 waves: wm=w>>2, wn=w&3), grid 256
// (every CU busy; B traffic HALVED to 128 MB). LDS dbuf 2x48KB = 96KB:
//   per buf (shorts): A_hi[ks8][row64][e8] @0, A_lo @4096,
//                     B_hi[ks8][col128][e8] @8192, B_lo @16384.
// B staged via REGULAR vector loads (reg-staged, issue-early/write-late);
// A reg-staged + pk-cvt.
// ---------------------------------------------------------------------------
#define K1BUF 24576   // shorts per buffer (48 KB)

__global__ __launch_bounds__(512) void caps_primary(
    const float* __restrict__ x, const unsigned short* __restrict__ bth,
    const unsigned short* __restrict__ btl, const float* __restrict__ bp,
    float* __restrict__ p_out)
{
  __shared__ unsigned short lds[2 * K1BUF];   // 96 KB
  const int tid  = threadIdx.x;
  const int lane = tid & 63;
  const int w    = tid >> 6;       // 0..7
  const int wm   = w >> 2;         // 0..1 -> rows wm*32..+31
  const int wn   = w & 3;          // 0..3 -> cols wn*32..+31
  const int lc   = lane & 31;
  const int hi   = lane >> 5;
  const int row0 = blockIdx.x * 64;

  const int rowA = tid & 63;       // A staging: (row=rowA, ks=kgA)
  const int kgA  = tid >> 6;       // 0..7
  const float* xrow = x + (size_t)(row0 + rowA) * 1024 + kgA * 8;

  f32x16 acc;
#pragma unroll
  for (int j = 0; j < 16; ++j) acc[j] = 0.f;

  float4 a0, a1;
  u16x8 b0, b1, b2, b3;

#define A_LOAD(kt) do { const float* xp_ = xrow + (kt) * 64; \
    a0 = *(const float4*)(xp_); a1 = *(const float4*)(xp_ + 4); } while (0)

#define B_LOAD(kt) do { \
    const unsigned short* gh_ = bth + ((size_t)(kt) * 1024) * 8; \
    const unsigned short* gl_ = btl + ((size_t)(kt) * 1024) * 8; \
    b0 = *(const u16x8*)(gh_ + (size_t)tid * 8); \
    b1 = *(const u16x8*)(gh_ + (size_t)(512 + tid) * 8); \
    b2 = *(const u16x8*)(gl_ + (size_t)tid * 8); \
    b3 = *(const u16x8*)(gl_ + (size_t)(512 + tid) * 8); } while (0)

#define AB_WRITE(bufi) do { u16x8 h_, l_; cvt8pk(a0, a1, h_, l_); \
    unsigned short* B_ = lds + (bufi) * K1BUF; \
    *(u16x8*)(B_ + (kgA * 64 + rowA) * 8) = h_; \
    *(u16x8*)(B_ + 4096 + (kgA * 64 + rowA) * 8) = l_; \
    *(u16x8*)(B_ + 8192  + tid * 8) = b0; \
    *(u16x8*)(B_ + 8192  + (512 + tid) * 8) = b1; \
    *(u16x8*)(B_ + 16384 + tid * 8) = b2; \
    *(u16x8*)(B_ + 16384 + (512 + tid) * 8) = b3; } while (0)

#define COMPUTE(bufi) do { \
    const unsigned short* F = lds + (bufi) * K1BUF; \
    _Pragma("unroll") \
    for (int kk = 0; kk < 4; ++kk) { \
      const int ks = kk * 2 + hi; \
      bf16x8 ah  = *(const bf16x8*)(F + (ks * 64 + wm * 32 + lc) * 8); \
      bf16x8 al  = *(const bf16x8*)(F + 4096 + (ks * 64 + wm * 32 + lc) * 8); \
      bf16x8 bh  = *(const bf16x8*)(F + 8192  + (ks * 128 + wn * 32 + lc) * 8); \
      bf16x8 blo = *(const bf16x8*)(F + 16384 + (ks * 128 + wn * 32 + lc) * 8); \
      acc = MFMA32(ah, bh,  acc); \
      acc = MFMA32(ah, blo, acc); \
      acc = MFMA32(al, bh,  acc); \
    } } while (0)

  // prologue
  A_LOAD(0);
  B_LOAD(0);
  AB_WRITE(0);
  __syncthreads();

#pragma unroll 2
  for (int kt = 0; kt < 16; ++kt) {
    const int cur = kt & 1;
    if (kt < 15) {
      A_LOAD(kt + 1);   // issue global loads EARLY (latency hides under COMPUTE)
      B_LOAD(kt + 1);
    }
    COMPUTE(cur);
    if (kt < 15) AB_WRITE(cur ^ 1);
    __syncthreads();
  }
#undef A_LOAD
#undef B_LOAD
#undef AB_WRITE
#undef COMPUTE

  // epilogue: bias + per-capsule squash.
  // C/D 32x32: col = wn*32 + lc, row = wm*32 + (r&3) + 8*(r>>2) + 4*hi.
  const int col = wn * 32 + lc;
  const float bpv = bp[col];
#pragma unroll
  for (int r = 0; r < 16; ++r) {
    const int row = wm * 32 + (r & 3) + 8 * (r >> 2) + 4 * hi;
    float val = acc[r] + bpv;
    float sq = val * val;
    sq += __shfl_xor(sq, 1); sq += __shfl_xor(sq, 2);
    sq += __shfl_xor(sq, 4); sq += __shfl_xor(sq, 8);
    float sc = (sq / (1.f + sq)) / sqrtf(sq + 1e-8f);
    p_out[(size_t)(row0 + row) * 128 + col] = val * sc;
  }
}

// ---------------------------------------------------------------------------
// K2: routing as 3 fused MFMA passes (verified round 11, unchanged).
// ---------------------------------------------------------------------------
__global__ __launch_bounds__(512) void caps_route_g(
    const float* __restrict__ p_in, const unsigned short* __restrict__ mh,
    const unsigned short* __restrict__ ml, float* __restrict__ cs_out)
{
  __shared__ float pT[128 * 65];          // [k][row], 33.3 KB, conflict-free reads
  __shared__ unsigned short Msh[32768];   // M split: hi @0, lo @16384
  __shared__ float t_lds[64 * 9];
  __shared__ float c_lds[64 * 9];
  const int tid  = threadIdx.x;
  const int lane = tid & 63;
  const int w    = tid >> 6;
  const int wm   = w >> 2;         // 0..1 -> rows wm*32..+31
  const int wn   = w & 3;          // 0..3 -> cols wn*32..+31
  const int lc   = lane & 31;
  const int hi   = lane >> 5;
  const int row0 = blockIdx.x * 64;

  // stage M (coalesced u16x8, linear layout preserved)
#pragma unroll
  for (int i = 0; i < 4; ++i) {
    int idx = tid + i * 512;   // 2048 chunks
    *(u16x8*)&Msh[idx * 8] = *(const u16x8*)(mh + (size_t)idx * 8);
    *(u16x8*)&Msh[16384 + idx * 8] = *(const u16x8*)(ml + (size_t)idx * 8);
  }
  // stage p transposed (coalesced global reads; scalar LDS scatter)
#pragma unroll
  for (int i = 0; i < 4; ++i) {
    int j = tid + i * 512;
    int r = j >> 5, c4 = j & 31;
    f32x4 v = *(const f32x4*)(p_in + (size_t)(row0 + r) * 128 + c4 * 4);
    pT[(c4 * 4 + 0) * 65 + r] = v[0];
    pT[(c4 * 4 + 1) * 65 + r] = v[1];
    pT[(c4 * 4 + 2) * 65 + r] = v[2];
    pT[(c4 * 4 + 3) * 65 + r] = v[3];
  }
  if (w == 0) {
#pragma unroll
    for (int n = 0; n < 8; ++n) c_lds[lane * 9 + n] = 0.125f;
  }
  __syncthreads();

  const int arow = wm * 32 + lc;   // A row for this lane
  const int col  = wn * 32 + lc;   // output col for this lane
  const int cap  = wn * 2 + (lc >> 4);
  float bb[8] = {0.f, 0.f, 0.f, 0.f, 0.f, 0.f, 0.f, 0.f};   // wave-0 state

#pragma unroll 1
  for (int it = 0; it < 3; ++it) {
    f32x16 acc;
#pragma unroll
    for (int j = 0; j < 16; ++j) acc[j] = 0.f;

    // Y = (c o p) @ M : 8 k-steps, capsule n == k-step kk
#pragma unroll
    for (int kk = 0; kk < 8; ++kk) {
      const float cv = c_lds[arow * 9 + kk];
      float q[8];
#pragma unroll
      for (int e = 0; e < 8; ++e)
        q[e] = pT[(kk * 16 + hi * 8 + e) * 65 + arow] * cv;
      u16x8 hq, lq;
      cvt8pk_a(q, hq, lq);
      const int fi = ((kk * 2 + hi) * 128 + col) * 8;
      bf16x8 mbh = *(const bf16x8*)&Msh[fi];
      bf16x8 mbl = *(const bf16x8*)&Msh[16384 + fi];
      acc = MFMA32(*(bf16x8*)&hq, mbh, acc);
      acc = MFMA32(*(bf16x8*)&hq, mbl, acc);
      acc = MFMA32(*(bf16x8*)&lq, mbh, acc);
    }

    // t partials: per r, prod = p[row][col] * Y[row][col], reduce 16 lanes
    float tp[16];
#pragma unroll
    for (int r = 0; r < 16; ++r) {
      const int row = wm * 32 + (r & 3) + 8 * (r >> 2) + 4 * hi;
      float prod = pT[col * 65 + row] * acc[r];
      prod += __shfl_xor(prod, 1);
      prod += __shfl_xor(prod, 2);
      prod += __shfl_xor(prod, 4);
      prod += __shfl_xor(prod, 8);
      tp[r] = prod;
    }
    __syncthreads();                 // wave0's previous t-read done
    if ((lc & 15) == 0) {
#pragma unroll
      for (int r = 0; r < 16; ++r) {
        const int row = wm * 32 + (r & 3) + 8 * (r >> 2) + 4 * hi;
        t_lds[row * 9 + cap] = tp[r];
      }
    }
    __syncthreads();

    if (w == 0) {
      float c[8], t[8];
#pragma unroll
      for (int n = 0; n < 8; ++n) {
        c[n] = c_lds[lane * 9 + n];
        t[n] = t_lds[lane * 9 + n];
      }
      float ss = 0.f;
#pragma unroll
      for (int n = 0; n < 8; ++n) ss = fmaf(c[n], t[n], ss);
      float scale = (ss / (1.f + ss)) / sqrtf(ss + 1e-8f);
      if (it < 2) {
#pragma unroll
        for (int n = 0; n < 8; ++n) bb[n] += scale * t[n];
        float mx = bb[0];
#pragma unroll
        for (int n = 1; n < 8; ++n) mx = fmaxf(mx, bb[n]);
        float e[8], Z = 0.f;
#pragma unroll
        for (int n = 0; n < 8; ++n) { e[n] = expf(bb[n] - mx); Z += e[n]; }
        float inv = 1.f / Z;
#pragma unroll
        for (int n = 0; n < 8; ++n) c_lds[lane * 9 + n] = e[n] * inv;
      } else {
        f32x4 c0 = {scale * c[0], scale * c[1], scale * c[2], scale * c[3]};
        f32x4 c1 = {scale * c[4], scale * c[5], scale * c[6], scale * c[7]};
        *(f32x4*)(cs_out + (size_t)(row0 + lane) * 8)     = c0;
        *(f32x4*)(cs_out + (size_t)(row0 + lane) * 8 + 4) = c1;
      }
    }
    __syncthreads();
  }
}

// ---------------------------------------------------------------------------
// K3: v = (cs.p) @ Wflat  [16384,128]x[128,512] split-bf16 via 32x32x16 MFMA.
// cs folded into A-fragment load (q never materialized). (verified round 10)
// ---------------------------------------------------------------------------
__global__ __launch_bounds__(512) void caps_vout(
    const float* __restrict__ p, const unsigned short* __restrict__ bth,
    const unsigned short* __restrict__ btl, const float* __restrict__ cs,
    float* __restrict__ out)
{
  __shared__ unsigned short Bsh[32768];   // hi @0, lo @16384 (ushorts)
  const int tid  = threadIdx.x;
  const int lane = tid & 63;
  const int w    = tid >> 6;
  const int wm   = w >> 2;         // 0..1 -> rows wm*32..+31
  const int wn   = w & 3;          // 0..3 -> cols wn*32..+31
  const int lc   = lane & 31;
  const int hi   = lane >> 5;
  const int row0 = blockIdx.x * 64;
  const int col0 = blockIdx.y * 128;

#pragma unroll
  for (int i = 0; i < 4; ++i) {
    int idx = tid + i * 512;               // 2048 chunks
    int kt = idx >> 10, kg = (idx >> 7) & 7, col = idx & 127;
    size_t g = ((size_t)(kt * 8 + kg) * 512 + col0 + col) * 8;
    *(u16x8*)&Bsh[idx * 8] = *(const u16x8*)(bth + g);
    *(u16x8*)&Bsh[16384 + idx * 8] = *(const u16x8*)(btl + g);
  }

  const int rA = row0 + wm * 32 + lc;
  const float* qp = p + (size_t)rA * 128;
  float cs8[8];
  *(f32x4*)&cs8[0] = *(const f32x4*)(cs + (size_t)rA * 8);
  *(f32x4*)&cs8[4] = *(const f32x4*)(cs + (size_t)rA * 8 + 4);
  __syncthreads();

  f32x16 acc;
#pragma unroll
  for (int j = 0; j < 16; ++j) acc[j] = 0.f;

#pragma unroll
  for (int kt = 0; kt < 2; ++kt) {
#pragma unroll
    for (int kk = 0; kk < 4; ++kk) {
      const float* qk = qp + kt * 64 + kk * 16 + hi * 8;
      float4 a0 = *(const float4*)(qk);
      float4 a1 = *(const float4*)(qk + 4);
      const float cv = cs8[kt * 4 + kk];   // capsule n = k/16
      a0.x *= cv; a0.y *= cv; a0.z *= cv; a0.w *= cv;
      a1.x *= cv; a1.y *= cv; a1.z *= cv; a1.w *= cv;
      bf16x8 ah, al;
      cvt8b(a0, a1, ah, al);
      const int ks = kk * 2 + hi;
      const int fi = ((kt * 8 + ks) * 128 + wn * 32 + lc) * 8;
      bf16x8 bh  = *(const bf16x8*)&Bsh[fi];
      bf16x8 blo = *(const bf16x8*)&Bsh[16384 + fi];
      acc = MFMA32(ah, bh,  acc);
      acc = MFMA32(ah, blo, acc);
      acc = MFMA32(al, bh,  acc);
    }
  }

#pragma unroll
  for (int r = 0; r < 16; ++r) {
    const int row = (r & 3) + 8 * (r >> 2) + 4 * hi;
    out[(size_t)(row0 + wm * 32 + row) * 512 + col0 + wn * 32 + lc] = acc[r];
  }
}

extern "C" void kernel_launch(void* const* d_in, const int* in_sizes, int n_in,
                              void* d_out, int out_size, void* d_ws, size_t ws_size,
                              hipStream_t stream) {
  (void)in_sizes; (void)n_in; (void)out_size; (void)ws_size;
  const float* x  = (const float*)d_in[0];
  const float* Wp = (const float*)d_in[1];
  const float* bp = (const float*)d_in[2];
  const float* W  = (const float*)d_in[3];
  // d_in[4] = n_routing (fixed = 3)
  char* ws = (char*)d_ws;
  float* p_ws = (float*)ws;                                   // 8 MB
  unsigned short* th1 = (unsigned short*)(ws + 8388608);      // 256 KB
  unsigned short* tl1 = (unsigned short*)(ws + 8650752);      // 256 KB
  unsigned short* th2 = (unsigned short*)(ws + 8912896);      // 128 KB
  unsigned short* tl2 = (unsigned short*)(ws + 9043968);      // 128 KB
  unsigned short* th3 = (unsigned short*)(ws + 9175040);      // 32 KB (M hi)
  unsigned short* tl3 = (unsigned short*)(ws + 9207808);      // 32 KB (M lo)
  float* cs_ws = (float*)(ws + 9240576);                      // 512 KB
  float* outp = (float*)d_out;

  caps_prep_all<<<96, 256, 0, stream>>>(Wp, W, th1, tl1, th2, tl2, th3, tl3);
  caps_primary<<<256, 512, 0, stream>>>(x, th1, tl1, bp, p_ws);
  caps_route_g<<<256, 512, 0, stream>>>(p_ws, th3, tl3, cs_ws);
  caps_vout<<<dim3(256, 4), 512, 0, stream>>>(p_ws, th2, tl2, cs_ws, outp);
}